// Round 6
// baseline (197.721 us; speedup 1.0000x reference)
//
#include <hip/hip_runtime.h>
#include <hip/hip_bf16.h>
#include <hip/hip_fp16.h>

typedef unsigned int   uint;
typedef unsigned short ushort;

#define NB   8
#define NC   64
#define LL   32768
#define KK   5
#define NG   4
#define NDG  2
#define NGD  8        // NG*NDG
#define NCD  8        // NC / NGD
#define NOFF 40       // NGD*KK
#define DWK  7
#define XROW (LL + 16)   // xT row stride in positions (8 guard slots each side)

typedef _Float16 f16x8 __attribute__((ext_vector_type(8)));
typedef float    f32x4 __attribute__((ext_vector_type(4)));

__device__ __forceinline__ uint pkrtz(float a, float b) {
  typedef __fp16 fp16x2n __attribute__((ext_vector_type(2)));
  fp16x2n h = __builtin_amdgcn_cvt_pkrtz(a, b);
  union { fp16x2n h; uint u; } v; v.h = h; return v.u;
}

// ---------------------------------------------------------------------------
// k_prep: wtA/wtM raw folded layouts + Wf (deform A-frags, verified layout).
// ---------------------------------------------------------------------------
__global__ __launch_bounds__(256) void k_prep(
    const float* __restrict__ pwA, const float* __restrict__ pwM,
    const float* __restrict__ mw,
    float* __restrict__ wtA, float* __restrict__ wtM, ushort* __restrict__ Wf)
{
  int idx = blockIdx.x * 256 + threadIdx.x;
  if (idx < 2560) {
    int c = idx / 40, o = idx % 40;
    wtA[idx] = pwA[o * NC + c];
  } else if (idx < 5120) {
    int j = idx - 2560;
    int c = j / 40, o = j % 40;
    wtM[j] = pwM[o * NC + c];
  } else if (idx < 11264) {
    int j  = idx - 5120;          // [0, 6144)
    int jj = j & 7;
    int l  = (j >> 3) & 63;
    int gt = j >> 9;              // [0,12)
    int t  = gt % 3, g = gt / 3;
    int o  = l & 15;
    int kq = t * 32 + ((l >> 4) << 3) + jj;
    float val = 0.f;
    if (kq < 80) {
      int ktap = kq >> 3, c = kq & 7;
      int d = ktap / 5, kh = ktap % 5;
      val = mw[((g * 16 + o) * 16 + d * 8 + c) * KK + kh];
    }
    Wf[j] = __half_as_ushort(__float2half(val));
  }
}

// ---------------------------------------------------------------------------
// k_conv: depthwise conv7 both branches; 8 ch x 512 pos per block (grid 4096),
// each thread owns TWO 8-pos chunks with all loads issued up front (2x MLP vs
// the 256-pos version that profiled latency-bound at 3.55 TB/s).
// Output yAM interleaved: word(c,pos) = f16(yA) | f16(yM)<<16 (pkrtz, bit-
// identical values to the split buffers). Also emits xT (raw x f16, gather
// layout with guards) and per-channel stat partials (64 chunks per (b,ch)).
// ---------------------------------------------------------------------------
__device__ __forceinline__ void load8f(float* dst, const float* __restrict__ row,
                                       int start)
{
  if (start >= 0 && start + 8 <= LL) {
    float4 a = *(const float4*)(row + start);
    float4 b = *(const float4*)(row + start + 4);
    dst[0] = a.x; dst[1] = a.y; dst[2] = a.z; dst[3] = a.w;
    dst[4] = b.x; dst[5] = b.y; dst[6] = b.z; dst[7] = b.w;
  } else {
#pragma unroll
    for (int j = 0; j < 8; ++j) {
      int p = start + j;
      dst[j] = (p >= 0 && p < LL) ? row[p] : 0.f;
    }
  }
}

__device__ __forceinline__ void conv8(
    const float* __restrict__ v, const float* __restrict__ wa,
    const float* __restrict__ wm, float ba, float bm,
    float& sa, float& qa, float& sm, float& qm,
    uint4& y0, uint4& y1, uint4& xr)
{
  float ya8[8], ym8[8];
#pragma unroll
  for (int u = 0; u < 8; ++u) {
    float ya = ba, ym = bm;
#pragma unroll
    for (int j = 0; j < DWK; ++j) {
      float xv = v[5 + u + j];  // x[lb+u-3+j]
      ya += wa[j] * xv;
      ym += wm[j] * xv;
    }
    sa += ya; qa += ya * ya;
    sm += ym; qm += ym * ym;
    ya8[u] = ya; ym8[u] = ym;
  }
  y0.x = pkrtz(ya8[0], ym8[0]); y0.y = pkrtz(ya8[1], ym8[1]);
  y0.z = pkrtz(ya8[2], ym8[2]); y0.w = pkrtz(ya8[3], ym8[3]);
  y1.x = pkrtz(ya8[4], ym8[4]); y1.y = pkrtz(ya8[5], ym8[5]);
  y1.z = pkrtz(ya8[6], ym8[6]); y1.w = pkrtz(ya8[7], ym8[7]);
  xr.x = pkrtz(v[8],  v[9]);   xr.y = pkrtz(v[10], v[11]);
  xr.z = pkrtz(v[12], v[13]);  xr.w = pkrtz(v[14], v[15]);
}

__global__ __launch_bounds__(256) void k_conv(
    const float* __restrict__ x,
    const float* __restrict__ dwAw, const float* __restrict__ dwAb,
    const float* __restrict__ dwMw, const float* __restrict__ dwMb,
    uint* __restrict__ yAM,
    ushort* __restrict__ xT, float4* __restrict__ partial)
{
  __shared__ __align__(16) ushort lx[8 * 512];   // raw x f16 tile, 8 KB
  int tid  = threadIdx.x;
  int lblk = blockIdx.x & 63;
  int gd   = (blockIdx.x >> 6) & 7;
  int b    = blockIdx.x >> 9;
  int c    = tid >> 5;          // channel within gd group (0..7)
  int q    = tid & 31;          // 8-pos chunk within 256
  int l0   = lblk << 9;
  int lb0  = l0 + q * 8;
  int lb1  = lb0 + 256;
  int ch   = gd * 8 + c;
  const float* row = x + (size_t)(b * NC + ch) * LL;

  // issue ALL loads up front (12 dwordx4 in flight)
  float v0[24], v1[24];
  load8f(v0 + 0,  row, lb0 - 8);
  load8f(v0 + 8,  row, lb0);
  load8f(v0 + 16, row, lb0 + 8);
  load8f(v1 + 0,  row, lb1 - 8);
  load8f(v1 + 8,  row, lb1);
  load8f(v1 + 16, row, lb1 + 8);

  float wa[DWK], wm[DWK];
#pragma unroll
  for (int j = 0; j < DWK; ++j) {
    wa[j] = dwAw[ch * DWK + j];
    wm[j] = dwMw[ch * DWK + j];
  }
  float ba = dwAb[ch], bm = dwMb[ch];

  float sa = 0.f, qa = 0.f, sm = 0.f, qm = 0.f;
  uint* yb = yAM + (size_t)(b * NC + ch) * LL;
  {
    uint4 y0, y1, xr;
    conv8(v0, wa, wm, ba, bm, sa, qa, sm, qm, y0, y1, xr);
    *(uint4*)(yb + lb0)     = y0;
    *(uint4*)(yb + lb0 + 4) = y1;
    *(uint4*)(lx + c * 512 + q * 8) = xr;
  }
  {
    uint4 y0, y1, xr;
    conv8(v1, wa, wm, ba, bm, sa, qa, sm, qm, y0, y1, xr);
    *(uint4*)(yb + lb1)     = y0;
    *(uint4*)(yb + lb1 + 4) = y1;
    *(uint4*)(lx + c * 512 + 256 + q * 8) = xr;
  }

  // butterfly reduce over the 32 lanes sharing this channel
#pragma unroll
  for (int m = 1; m < 32; m <<= 1) {
    sa += __shfl_xor(sa, m);
    qa += __shfl_xor(qa, m);
    sm += __shfl_xor(sm, m);
    qm += __shfl_xor(qm, m);
  }
  if (q == 0)
    partial[((size_t)(b * NC + ch) << 6) + lblk] = make_float4(sa, qa, sm, qm);

  __syncthreads();
  size_t rowbase = (size_t)(b * NGD + gd) * (size_t)XROW;
#pragma unroll
  for (int half = 0; half < 2; ++half) {
    int pos = half * 256 + tid;
    uint4 pk;
    pk.x = (uint)lx[0 * 512 + pos] | ((uint)lx[1 * 512 + pos] << 16);
    pk.y = (uint)lx[2 * 512 + pos] | ((uint)lx[3 * 512 + pos] << 16);
    pk.z = (uint)lx[4 * 512 + pos] | ((uint)lx[5 * 512 + pos] << 16);
    pk.w = (uint)lx[6 * 512 + pos] | ((uint)lx[7 * 512 + pos] << 16);
    *(uint4*)(xT + (rowbase + 8 + (size_t)(l0 + pos)) * 8) = pk;
  }
  if (tid < 8) {
    uint4 z = {0, 0, 0, 0};
    if (lblk == 0)  *(uint4*)(xT + (rowbase + tid) * 8) = z;
    if (lblk == 63) *(uint4*)(xT + (rowbase + 8 + LL + tid) * 8) = z;
  }
}

// ---------------------------------------------------------------------------
// k_fin: reduce stat partials (64 chunks), fold GN into pointwise weights,
// emit per-batch f16 A-frags with PER-GROUP m-tiles for k_pd:
//   wFp[b][br][g][ks][lane][j] = fold(W)[c = ks*32+(lane>>4)*8+j][o = 10g+(lane&15)]
//   (rows (lane&15) >= 10 are zero pad);  biasPt[b][br][g][m].
// ---------------------------------------------------------------------------
__global__ __launch_bounds__(256) void k_fin(
    const float4* __restrict__ partial,
    const float* __restrict__ gnAw, const float* __restrict__ gnAb,
    const float* __restrict__ gnMw, const float* __restrict__ gnMb,
    const float* __restrict__ wtA, const float* __restrict__ wtM,
    const float* __restrict__ pbA, const float* __restrict__ pbM,
    ushort* __restrict__ wFp, float* __restrict__ biasPt)
{
  __shared__ float4 pr[256];
  __shared__ float gA[64], cA[64], gM[64], cM[64];
  __shared__ float sbA[40], sbM[40];
  int b = blockIdx.x;
  int t = threadIdx.x;
  {
    int c = t & 63, seg = t >> 6;
    const float4* pp = partial + ((size_t)(b * NC + c) << 6);
    float4 s = make_float4(0.f, 0.f, 0.f, 0.f);
    for (int i = seg; i < 64; i += 4) {
      float4 u = pp[i];
      s.x += u.x; s.y += u.y; s.z += u.z; s.w += u.w;
    }
    pr[t] = s;
  }
  __syncthreads();
  if (t < 64) {
    float4 a0 = pr[t], a1 = pr[t + 64], a2 = pr[t + 128], a3 = pr[t + 192];
    float sx = a0.x + a1.x + a2.x + a3.x;
    float sy = a0.y + a1.y + a2.y + a3.y;
    float sz = a0.z + a1.z + a2.z + a3.z;
    float sw = a0.w + a1.w + a2.w + a3.w;
    float mua = sx / LL, vara = sy / LL - mua * mua;
    float mum = sz / LL, varm = sw / LL - mum * mum;
    float ga = gnAw[t] * rsqrtf(vara + 1e-5f);
    float gm = gnMw[t] * rsqrtf(varm + 1e-5f);
    gA[t] = ga; cA[t] = gnAb[t] - mua * ga;
    gM[t] = gm; cM[t] = gnMb[t] - mum * gm;
  }
  __syncthreads();
  if (t < 40) {
    float sA = 0.f, sM = 0.f;
    for (int c = 0; c < 64; ++c) {
      sA += wtA[c * 40 + t] * cA[c];
      sM += wtM[c * 40 + t] * cM[c];
    }
    sbA[t] = 4.f * (pbA[t] + sA);
    sbM[t] = pbM[t] + sM;
  }
  // fragment weights (2 br x 4 g x 2 ks x 64 ln x 8 j = 8192)
  for (int idx = t; idx < 8192; idx += 256) {
    int br = idx >> 12;
    int e  = idx & 4095;
    int g  = e >> 10;
    int ks = (e >> 9) & 1;
    int ln = (e >> 3) & 63;
    int j  = e & 7;
    int rr = ln & 15;
    int c  = ks * 32 + ((ln >> 4) << 3) + j;
    float v = 0.f;
    if (rr < 10) {
      int o = 10 * g + rr;
      v = br ? wtM[c * 40 + o] * gM[c] : 4.f * wtA[c * 40 + o] * gA[c];
    }
    wFp[(size_t)b * 8192 + idx] = __half_as_ushort(__float2half(v));
  }
  __syncthreads();
  if (t < 128) {
    int br = t >> 6, g = (t >> 4) & 3, m = t & 15;
    float v = 0.f;
    if (m < 10) v = br ? sbM[10 * g + m] : sbA[10 * g + m];
    biasPt[b * 128 + t] = v;
  }
}

// ---------------------------------------------------------------------------
// k_pd: fused pointwise + softmax + deform over 64-position blocks.
// Phase 1 (point): wave w computes channels 10w..10w+9 for all 64 positions;
//   hs staged pre-interleaved (yAM word = A|M<<16) at byte
//   c*256 + ((pos*4)^(h(c)<<6)), h(c) = (c>>3)&3; B-frag = 8 ds_read_b32
//   stride 256 + v_perm split (2-way bank alias, free).
// Handoff: lane dumps its 10 (off, logit) f32 into its wave's private S
//   region, rereads per-position (same-wave DS ordering), softmax in f32.
// Phase 2 (deform): verified body, g = wave id, l = lb0+lane; setprio(1)
//   wraps MFMA clusters (waves are barrier-free/role-diverse here).
// ---------------------------------------------------------------------------
__global__ __launch_bounds__(256) void k_pd(
    const uint* __restrict__ yAM, const ushort* __restrict__ xT,
    const ushort* __restrict__ wFp, const float* __restrict__ biasPt,
    const ushort* __restrict__ Wf, const float* __restrict__ bias,
    float* __restrict__ out)
{
  __shared__ __align__(16) char S[4 * 12288];   // 48 KB
  int tid = threadIdx.x;
  int w   = tid >> 6;
  int ln  = tid & 63;
  int h   = ln >> 4;
  int col = ln & 15;
  int b   = blockIdx.x >> 9;
  int lb0 = (blockIdx.x & 511) << 6;

  // ---- stage interleaved h tiles (pre-interleaved in yAM) ----
  {
    const uint* src = yAM + (size_t)b * NC * LL + lb0;
#pragma unroll
    for (int i = 0; i < 4; ++i) {
      int fid = i * 256 + tid;          // 1024 = 64 c x 16 qc
      int c = fid >> 4, qc = fid & 15;
      uint4 wv = *(const uint4*)(src + (size_t)c * LL + qc * 4);
      *(uint4*)(S + c * 256 + ((qc << 4) ^ (((c >> 3) & 3) << 6))) = wv;
    }
  }

  // A-frags + bias (global loads overlap staging)
  const uint4* wFb = (const uint4*)(wFp + (size_t)b * 8192);
  f16x8 afA[2], afM[2];
#pragma unroll
  for (int ks = 0; ks < 2; ++ks) {
    union { uint4 u; f16x8 v; } cvA, cvM;
    cvA.u = wFb[(w * 2 + ks) * 64 + ln];
    cvM.u = wFb[512 + (w * 2 + ks) * 64 + ln];
    afA[ks] = cvA.v; afM[ks] = cvM.v;
  }
  f32x4 accA[4], accM[4];
  {
    float4 bvA = *(const float4*)(biasPt + b * 128 + w * 16 + h * 4);
    float4 bvM = *(const float4*)(biasPt + b * 128 + 64 + w * 16 + h * 4);
#pragma unroll
    for (int nt = 0; nt < 4; ++nt) {
      accA[nt][0]=bvA.x; accA[nt][1]=bvA.y; accA[nt][2]=bvA.z; accA[nt][3]=bvA.w;
      accM[nt][0]=bvM.x; accM[nt][1]=bvM.y; accM[nt][2]=bvM.z; accM[nt][3]=bvM.w;
    }
  }
  __syncthreads();

  // ---- point MFMAs ----
  __builtin_amdgcn_s_setprio(1);
#pragma unroll
  for (int nt = 0; nt < 4; ++nt) {
#pragma unroll
    for (int ks = 0; ks < 2; ++ks) {
      const char* gp = S + (ks * 32 + h * 8) * 256
                     + ((((nt * 16 + col) << 2)) ^ (h << 6));
      uint r0 = *(const uint*)(gp + 0 * 256);
      uint r1 = *(const uint*)(gp + 1 * 256);
      uint r2 = *(const uint*)(gp + 2 * 256);
      uint r3 = *(const uint*)(gp + 3 * 256);
      uint r4 = *(const uint*)(gp + 4 * 256);
      uint r5 = *(const uint*)(gp + 5 * 256);
      uint r6 = *(const uint*)(gp + 6 * 256);
      uint r7 = *(const uint*)(gp + 7 * 256);
      union { uint u[4]; f16x8 v; } bA, bM;
      bA.u[0] = __builtin_amdgcn_perm(r1, r0, 0x05040100u);
      bA.u[1] = __builtin_amdgcn_perm(r3, r2, 0x05040100u);
      bA.u[2] = __builtin_amdgcn_perm(r5, r4, 0x05040100u);
      bA.u[3] = __builtin_amdgcn_perm(r7, r6, 0x05040100u);
      bM.u[0] = __builtin_amdgcn_perm(r1, r0, 0x07060302u);
      bM.u[1] = __builtin_amdgcn_perm(r3, r2, 0x07060302u);
      bM.u[2] = __builtin_amdgcn_perm(r5, r4, 0x07060302u);
      bM.u[3] = __builtin_amdgcn_perm(r7, r6, 0x07060302u);
      accA[nt] = __builtin_amdgcn_mfma_f32_16x16x32_f16(afA[ks], bA.v,
                                                        accA[nt], 0, 0, 0);
      accM[nt] = __builtin_amdgcn_mfma_f32_16x16x32_f16(afM[ks], bM.v,
                                                        accM[nt], 0, 0, 0);
    }
  }
  __builtin_amdgcn_s_setprio(0);
  __syncthreads();   // all waves done reading hs before dumps overwrite it

  // ---- dump (off, logit) into wave-private region, reread per-position ----
  char* wb = S + w * 12288;
#pragma unroll
  for (int r = 0; r < 4; ++r) {
    int s = h * 4 + r;
    if (s < 10) {
#pragma unroll
      for (int nt = 0; nt < 4; ++nt) {
        int pos = nt * 16 + col;
        *(float*)(wb + (s << 8) + (pos << 2)) = accA[nt][r];
        *(float*)(wb + 2560 + (s << 8) + (pos << 2)) = accM[nt][r];
      }
    }
  }
  // same-wave DS ordering guarantees dump visibility for these reads
  float off[10], lg[10];
#pragma unroll
  for (int s = 0; s < 10; ++s) {
    off[s] = *(const float*)(wb + (s << 8) + (ln << 2));
    lg[s]  = *(const float*)(wb + 2560 + (s << 8) + (ln << 2));
  }
  // softmax per 5-tap group, f32 (lane-local)
  float at[10];
  {
    float m0 = fmaxf(fmaxf(fmaxf(lg[0], lg[1]), fmaxf(lg[2], lg[3])), lg[4]);
    float m1 = fmaxf(fmaxf(fmaxf(lg[5], lg[6]), fmaxf(lg[7], lg[8])), lg[9]);
    float e[10], s0 = 0.f, s1 = 0.f;
#pragma unroll
    for (int j = 0; j < 5; ++j) { e[j] = __expf(lg[j] - m0); s0 += e[j]; }
#pragma unroll
    for (int j = 5; j < 10; ++j) { e[j] = __expf(lg[j] - m1); s1 += e[j]; }
    float r0 = 1.f / s0, r1 = 1.f / s1;
#pragma unroll
    for (int j = 0; j < 5; ++j)  at[j] = e[j] * r0;
#pragma unroll
    for (int j = 5; j < 10; ++j) at[j] = e[j] * r1;
  }

  // ---- deform phase: g = wave id, position l = lb0 + ln ----
  int g = w;
  int l = lb0 + ln;

  f16x8 af[3];
#pragma unroll
  for (int t = 0; t < 3; ++t) {
    union { uint4 u; f16x8 hh; } cv;
    cv.u = ((const uint4*)Wf)[(g * 3 + t) * 64 + ln];
    af[t] = cv.hh;
  }
  int orow = (ln >> 4) << 2;
  float4 b4 = *(const float4*)(bias + g * 16 + orow);
  f32x4 acc[4];
#pragma unroll
  for (int nb = 0; nb < 4; ++nb) {
    acc[nb][0] = b4.x; acc[nb][1] = b4.y; acc[nb][2] = b4.z; acc[nb][3] = b4.w;
  }

  char* sb  = wb;                   // wave-private S tile (overwrites dump)
  int nbase = ln * 192;             // 96 f16 per row
  int msk   = (ln & 7) << 4;

  // zero the K-pad (kidx 80..95) -- after the rereads above
  {
    f16x8 Z = {};
    *(f16x8*)(sb + ((nbase + 160) ^ msk)) = Z;
    *(f16x8*)(sb + ((nbase + 176) ^ msk)) = Z;
  }

#pragma unroll
  for (int d = 0; d < NDG; ++d) {
    const ushort* xr = xT + (size_t)(b * NGD + g * 2 + d) * (size_t)XROW * 8;
#pragma unroll
    for (int kh = 0; kh < KK; ++kh) {
      int s = d * KK + kh;
      float p = (float)(l - 2 + kh) + off[s];
      p = fminf(fmaxf(p, -1.f), 32768.f);
      float p0f = floorf(p);
      float w1  = p - p0f;
      int   i0  = (int)p0f;
      float f0 = (1.f - w1) * at[s];
      float f1 = w1 * at[s];
      _Float16 a0 = (_Float16)f0;
      _Float16 a1 = (_Float16)f1;
      f16x8 F0 = {a0, a0, a0, a0, a0, a0, a0, a0};
      f16x8 F1 = {a1, a1, a1, a1, a1, a1, a1, a1};
      const ushort* q = xr + (size_t)(i0 + 8) * 8;
      f16x8 X0 = *(const f16x8*)q;
      f16x8 X1 = *(const f16x8*)(q + 8);
      f16x8 S8 = X0 * F0 + X1 * F1;
      *(f16x8*)(sb + ((nbase + s * 16) ^ msk)) = S8;
    }
  }

  int rb0 = (ln & 15) * 192 + ((ln >> 4) << 4);
  __builtin_amdgcn_s_setprio(1);
#pragma unroll
  for (int nb = 0; nb < 4; ++nb) {
#pragma unroll
    for (int t = 0; t < 3; ++t) {
      f16x8 bf = *(const f16x8*)(sb + ((rb0 + nb * 3072 + t * 64) ^ msk));
      acc[nb] = __builtin_amdgcn_mfma_f32_16x16x32_f16(af[t], bf, acc[nb],
                                                       0, 0, 0);
    }
  }
  __builtin_amdgcn_s_setprio(0);

  float* ob = out + (size_t)(b * NC + g * 16 + orow) * LL + lb0 + (ln & 15);
#pragma unroll
  for (int nb = 0; nb < 4; ++nb) {
#pragma unroll
    for (int r = 0; r < 4; ++r)
      ob[(size_t)r * LL + (nb << 4)] = acc[nb][r];
  }
}

// ---------------------------------------------------------------------------
extern "C" void kernel_launch(void* const* d_in, const int* in_sizes, int n_in,
                              void* d_out, int out_size, void* d_ws, size_t ws_size,
                              hipStream_t stream)
{
  const float* x    = (const float*)d_in[0];
  const float* dwAw = (const float*)d_in[1];
  const float* dwAb = (const float*)d_in[2];
  const float* gnAw = (const float*)d_in[3];
  const float* gnAb = (const float*)d_in[4];
  const float* pwAw = (const float*)d_in[5];
  const float* pwAb = (const float*)d_in[6];
  const float* dwMw = (const float*)d_in[7];
  const float* dwMb = (const float*)d_in[8];
  const float* gnMw = (const float*)d_in[9];
  const float* gnMb = (const float*)d_in[10];
  const float* pwMw = (const float*)d_in[11];
  const float* pwMb = (const float*)d_in[12];
  const float* mw   = (const float*)d_in[13];
  const float* bias = (const float*)d_in[14];
  float* out = (float*)d_out;

  // Workspace (~102 MB total):
  float* wtA = (float*)d_ws;                       // 2560 f
  float* wtM = wtA + 2560;                         // 2560 f
  ushort* Wf = (ushort*)(wtM + 2560);              // 6144 us
  ushort* wFp = Wf + 6144;                         // 8*8192 us (128 KB)
  float* biasPt = (float*)(wFp + 65536);           // 8*128 f
  float4* partial = (float4*)(biasPt + 1024);      // 32K float4 used (512 KB)
  uint* yAM = (uint*)(partial + 65536);            // 16.78M uint (67 MB)
  ushort* xT = (ushort*)(yAM + (size_t)NB * NC * LL); // 16.79M us (33.6 MB)

  hipLaunchKernelGGL(k_prep, dim3(44), dim3(256), 0, stream,
                     pwAw, pwMw, mw, wtA, wtM, Wf);
  hipLaunchKernelGGL(k_conv, dim3(NB * NGD * 64), dim3(256), 0, stream,
                     x, dwAw, dwAb, dwMw, dwMb, yAM, xT, partial);
  hipLaunchKernelGGL(k_fin, dim3(NB), dim3(256), 0, stream,
                     partial, gnAw, gnAb, gnMw, gnMb, wtA, wtM, pwAb, pwMb,
                     wFp, biasPt);
  hipLaunchKernelGGL(k_pd, dim3(NB * 512), dim3(256), 0, stream,
                     yAM, xT, wFp, biasPt, Wf, bias, out);
}